// Round 15
// baseline (370.916 us; speedup 1.0000x reference)
//
#include <hip/hip_runtime.h>

// TransformerHead: B=4, S=4096, D_MODEL=1024, D_K=64.  All-bf16 MFMA pipeline.
//   ws layout: xb(32MB) | Wcat(2.25MB) | qk(4MB) | vT(32MB)  ~= 70.4MB
// R1: T2 XOR-swizzle (conflicts 1.09e8 -> 0).  R3: swapped QK.  R4/R6: cvt_pk asm
// BANNED.  R9: per-lane strided global V gathers BANNED (FETCH 26x).
// R5/R7/R8/R10: conflict-free writes; stats_k dropped; VALU diet; fused cast: 249us.
// R11: s-tile 64, V gload16 single-buf, counted vmcnt: 240.2us (pv 178.5).
// R12: QK-one-tile-ahead FAILED (same-wave MFMA pipe -> no overlap). Reverted.
// R13: QK retile 2s x 4q (kf reads 8->4): 235.4us (pv 170.5, MfmaUtil 45.3).
// R14: QK retile 4s x 2q (wave = 16s x 64q): kf reads 4 -> 2; LDS reads/wave-tile
//      20 -> 18.  qf[2][4] (+16 VGPR, occupancy tripwire).  lsum = 4 per-quarter
//      partials via 512-float LDS table.  PV/staging/barriers byte-identical to R13.

#define DEV static __device__ __forceinline__

typedef __attribute__((ext_vector_type(8))) short bf16x8;
typedef __attribute__((ext_vector_type(4))) float f32x4;
typedef __attribute__((ext_vector_type(4))) unsigned short u16x4;
typedef __attribute__((ext_vector_type(8))) unsigned short u16x8;
typedef __attribute__((address_space(1))) void as1_void;
typedef __attribute__((address_space(3))) void as3_void;

DEV unsigned short f2bf(float f) {
  union { float f; unsigned u; } v; v.f = f;
  return (unsigned short)((v.u + 0x7FFFu + ((v.u >> 16) & 1u)) >> 16);
}

// pack bf16(a) (low16) | bf16(b) (high16), round-half-up, via v_perm_b32
DEV unsigned pk_bf16(float a, float b) {
  union { float f; unsigned u; } va, vb;
  va.f = a; vb.f = b;
  return __builtin_amdgcn_perm(vb.u + 0x8000u, va.u + 0x8000u, 0x07060302u);
}

DEV void gload16(const void* g, void* l) {
  __builtin_amdgcn_global_load_lds((as1_void*)g, (as3_void*)l, 16, 0, 0);
}

// 128B-row swizzle (rows of 64 bf16)
DEV int swz(int row, int cb) { return (row << 7) + (cb ^ ((row & 7) << 4)); }

// ---------------------------------------------------------------- fused cast f32->bf16
__global__ __launch_bounds__(256) void cast_all_k(
    const float* __restrict__ x, const float* __restrict__ wq,
    const float* __restrict__ wk, const float* __restrict__ wv,
    unsigned short* __restrict__ xb, unsigned short* __restrict__ wcat, float sq) {
  const int stride = gridDim.x * blockDim.x;
  for (int i = blockIdx.x * blockDim.x + threadIdx.x; i < 2244608; i += stride) {
    const float* src; unsigned short* dst; float scale; int j;
    if (i < 2097152)      { src = x;  dst = xb;            scale = 1.f; j = i; }
    else if (i < 2105344) { src = wq; dst = wcat;          scale = sq;  j = i - 2097152; }
    else if (i < 2113536) { src = wk; dst = wcat + 65536;  scale = 1.f; j = i - 2105344; }
    else                  { src = wv; dst = wcat + 131072; scale = 1.f; j = i - 2113536; }
    const float4* p = (const float4*)src + (size_t)j * 2;
    float4 a = p[0], b = p[1];
    u16x8 r;
    r[0] = f2bf(a.x * scale); r[1] = f2bf(a.y * scale);
    r[2] = f2bf(a.z * scale); r[3] = f2bf(a.w * scale);
    r[4] = f2bf(b.x * scale); r[5] = f2bf(b.y * scale);
    r[6] = f2bf(b.z * scale); r[7] = f2bf(b.w * scale);
    *(u16x8*)(dst + (size_t)j * 8) = r;
  }
}

// ---------------------------------------------------------------- QKV projection GEMM (unchanged)
__global__ __launch_bounds__(256, 2) void gemm_qkv_k(
    const unsigned short* __restrict__ xb, const unsigned short* __restrict__ wcat,
    unsigned short* __restrict__ qk, unsigned short* __restrict__ vT) {
  __shared__ __align__(16) unsigned char smem[65536];
  unsigned char* sA = smem;          // 2 x [128][64] bf16, swizzled
  unsigned char* sB = smem + 32768;  // 2 x [128][64] bf16, swizzled
  const int tid = threadIdx.x;
  const int w = tid >> 6, lane = tid & 63, lo = lane & 15, hi = lane >> 4;
  const int wr = w >> 1, wc = w & 1;
  const int bn = blockIdx.x, m0 = blockIdx.y * 128, n0 = bn * 128;
  const char* aBase = (const char*)xb + (size_t)m0 * 2048;
  const char* bBase = (const char*)wcat + (size_t)n0 * 2048;

  const int soff = ((w * 4) << 10) + (lane << 4);
  f32x4 acc[4][4];
  const f32x4 z = {0.f, 0.f, 0.f, 0.f};
#pragma unroll
  for (int mi = 0; mi < 4; ++mi)
#pragma unroll
    for (int ni = 0; ni < 4; ++ni) acc[mi][ni] = z;

#pragma unroll
  for (int r2 = 0; r2 < 4; ++r2) {
    const int off = soff + (r2 << 10);
    const int row = off >> 7;
    const int cbs = (off & 127) ^ ((row & 7) << 4);
    gload16(aBase + (size_t)row * 2048 + cbs, sA + ((w * 4 + r2) << 10));
    gload16(bBase + (size_t)row * 2048 + cbs, sB + ((w * 4 + r2) << 10));
  }
  __syncthreads();

  int cur = 0;
  for (int k0 = 0; k0 < 1024; k0 += 64) {
    if (k0 + 64 < 1024) {
      const int nb = (cur ^ 1) * 16384;
#pragma unroll
      for (int r2 = 0; r2 < 4; ++r2) {
        const int off = soff + (r2 << 10);
        const int row = off >> 7;
        const int cbs = (off & 127) ^ ((row & 7) << 4);
        gload16(aBase + (size_t)row * 2048 + (k0 + 64) * 2 + cbs, sA + nb + ((w * 4 + r2) << 10));
        gload16(bBase + (size_t)row * 2048 + (k0 + 64) * 2 + cbs, sB + nb + ((w * 4 + r2) << 10));
      }
    }
    const int cb0 = cur * 16384;
#pragma unroll
    for (int kk = 0; kk < 2; ++kk) {
      const int cb = kk * 64 + hi * 16;
      bf16x8 af[4], bfv[4];
#pragma unroll
      for (int mi = 0; mi < 4; ++mi)
        af[mi] = *(const bf16x8*)(sA + cb0 + swz(wr * 64 + mi * 16 + lo, cb));
#pragma unroll
      for (int ni = 0; ni < 4; ++ni)
        bfv[ni] = *(const bf16x8*)(sB + cb0 + swz(wc * 64 + ni * 16 + lo, cb));
#pragma unroll
      for (int mi = 0; mi < 4; ++mi)
#pragma unroll
        for (int ni = 0; ni < 4; ++ni)
          acc[mi][ni] = __builtin_amdgcn_mfma_f32_16x16x32_bf16(af[mi], bfv[ni], acc[mi][ni], 0, 0, 0);
    }
    __syncthreads();
    cur ^= 1;
  }

  if (bn == 0) {
#pragma unroll
    for (int mi = 0; mi < 4; ++mi) {
      const int row = m0 + wr * 64 + mi * 16 + hi * 4;
#pragma unroll
      for (int ni = 0; ni < 4; ++ni) {
        const int col = wc * 64 + ni * 16 + lo;
#pragma unroll
        for (int r = 0; r < 4; ++r)
          qk[(size_t)(row + r) * 128 + col] = f2bf(acc[mi][ni][r]);
      }
    }
  } else {
#pragma unroll
    for (int mi = 0; mi < 4; ++mi) {
      const int grow = m0 + wr * 64 + mi * 16 + hi * 4;
      const int b = grow >> 12, s = grow & 4095;
#pragma unroll
      for (int ni = 0; ni < 4; ++ni) {
        const int vcol = (n0 - 128) + wc * 64 + ni * 16 + lo;
        u16x4 pk;
#pragma unroll
        for (int r = 0; r < 4; ++r) pk[r] = f2bf(acc[mi][ni][r]);
        *(u16x4*)(vT + (size_t)(b * 1024 + vcol) * 4096 + s) = pk;
      }
    }
  }
}

// ---------------------------------------------------------------- PV pass (R14)
// Block: 128 q x 256 v, 8 waves, s-tile 64.  QK wave grid: 4(s-quarter) x 2(q-half),
// wave = 16s x 64q -> 2 kf reads (was 4).  PV wave grid: 2x4 (64q x 64v) as R11/R13.
// LDS: sK 2x[64][128B] 16KB | sV [256][128B] 32KB single | sP [128][128B] 16KB = 64KB.
__global__ __launch_bounds__(512, 4) void pv_k(
    const unsigned short* __restrict__ qk, const unsigned short* __restrict__ vT,
    float* __restrict__ out) {
  __shared__ __align__(16) unsigned char smem[65536];
  unsigned char* sK = smem;          // 2 x [64][128B], swz128
  unsigned char* sV = smem + 16384;  // [256][128B] single buf, swz128
  unsigned char* sP = smem + 49152;  // [128][128B], swz128
  const int tid = threadIdx.x;
  const int w = tid >> 6, lane = tid & 63, lo = lane & 15, hi = lane >> 4;
  const int wr = w >> 2, wc = w & 3;   // PV role: 2x4 wave grid over 128x256
  const int sh = w & 3, qg = w >> 2;   // QK role: s-quarter x q-half (16s x 64q)
  const int ck = blockIdx.x, qt = blockIdx.y, b = blockIdx.z;
  const char* qkB = (const char*)qk;
  const char* vTB = (const char*)vT;
  const size_t qrow0 = (size_t)(b * 4096 + qt * 128);
  const f32x4 z = {0.f, 0.f, 0.f, 0.f};

  // Q frags (pre-scaled by 0.125*log2e at cast): 4 q-subgroups x 2 kk, global -> regs once.
  bf16x8 qf[2][4];
#pragma unroll
  for (int kk = 0; kk < 2; ++kk)
#pragma unroll
    for (int j = 0; j < 4; ++j)
      qf[kk][j] = *(const bf16x8*)(qkB + (qrow0 + qg * 64 + j * 16 + lo) * 256 + kk * 64 + hi * 16);
  float lsum[4] = {0.f, 0.f, 0.f, 0.f};  // partials for q = qg*64 + j*16 + lo, this wave's 16 s

  // K staging: tile [64s][64d]=8KB, 1 issue/wave; chunk kc: row=kc>>3, g=kc&7
  const int kc = w * 64 + lane;
  const int kRow = kc >> 3, kG = kc & 7;
  const char* kSrc = qkB + (size_t)(b * 4096 + kRow) * 256 + 128 + ((kG ^ (kRow & 7)) << 4);
  unsigned char* kDst = sK + (kc << 4);  // + buf*8192

  // V staging: tile [256v][64s]=32KB, 4 issues/lane; pre-swizzled source (rule #21)
  const char* vSrcJ[4];
#pragma unroll
  for (int j = 0; j < 4; ++j) {
    const int c = tid + j * 512;
    const int row = c >> 3, g = c & 7;
    vSrcJ[j] = vTB + (size_t)(b * 1024 + ck * 256 + row) * 8192 + ((g ^ (row & 7)) << 4);
  }

  // sP b64 write addrs: row q = qg*64 + j*16 + lo (q&7 == lo&7); s0 = sh*16 + 4*hi
  // granule = 2*sh + (hi>>1), slot XOR (lo&7); +8B for hi&1.  8 distinct slots/8-lane grp.
  const int lx7 = (lo & 7) << 4;
  const int pCol = (((2 * sh + (hi >> 1)) << 4) ^ lx7) + ((hi & 1) << 3);
  int aP[4];
#pragma unroll
  for (int j = 0; j < 4; ++j)
    aP[j] = ((qg * 64 + j * 16 + lo) << 7) + pCol;

  f32x4 acc[4][4];
#pragma unroll
  for (int mi = 0; mi < 4; ++mi)
#pragma unroll
    for (int ni = 0; ni < 4; ++ni) acc[mi][ni] = z;

  // prologue: V(0) + K(0) -> full drain
#pragma unroll
  for (int j = 0; j < 4; ++j) gload16(vSrcJ[j], sV + ((tid + j * 512) << 4));
  gload16(kSrc, kDst);
  __syncthreads();  // drains vmcnt(0) lgkmcnt(0)

  int cur = 0;
  for (int t = 0; t < 64; ++t) {
    // K(t+1) -> buf^1 (wraps harmlessly at t=63 to keep vmcnt counts uniform)
    gload16(kSrc + (size_t)((t + 1) & 63) * 16384, kDst + (cur ^ 1) * 8192);
    // ---- QK(t): wave computes S[sh*16 .. +16][qg*64 .. +64]; lane owns q cols
    f32x4 sv[4];
    sv[0] = z; sv[1] = z; sv[2] = z; sv[3] = z;
#pragma unroll
    for (int kk = 0; kk < 2; ++kk) {
      bf16x8 kf = *(const bf16x8*)(sK + cur * 8192 + swz(sh * 16 + lo, kk * 64 + hi * 16));
#pragma unroll
      for (int j = 0; j < 4; ++j)
        sv[j] = __builtin_amdgcn_mfma_f32_16x16x32_bf16(kf, qf[kk][j], sv[j], 0, 0, 0);
    }
    // ---- exp2 (unnormalized) + l partials + 4x b64 P writes
#pragma unroll
    for (int j = 0; j < 4; ++j) {
      const float p0 = __builtin_amdgcn_exp2f(sv[j][0]);
      const float p1 = __builtin_amdgcn_exp2f(sv[j][1]);
      const float p2 = __builtin_amdgcn_exp2f(sv[j][2]);
      const float p3 = __builtin_amdgcn_exp2f(sv[j][3]);
      lsum[j] += (p0 + p1) + (p2 + p3);
      uint2 d;
      d.x = pk_bf16(p0, p1);
      d.y = pk_bf16(p2, p3);
      *(uint2*)(sP + aP[j]) = d;
    }
    // ---- mid barrier: V(t) landed (vmcnt(1) leaves K(t+1) in flight), P visible
    asm volatile("s_waitcnt vmcnt(1) lgkmcnt(0)" ::: "memory");
    __builtin_amdgcn_sched_barrier(0);
    __builtin_amdgcn_s_barrier();
    __builtin_amdgcn_sched_barrier(0);
    // ---- PV(t): wave (wr,wc), rows wr*64..+64, cols wc*64..+64, k=64 (2 kk halves)
    __builtin_amdgcn_s_setprio(1);
#pragma unroll
    for (int kk = 0; kk < 2; ++kk) {
      bf16x8 pa[4];
#pragma unroll
      for (int mi = 0; mi < 4; ++mi)
        pa[mi] = *(const bf16x8*)(sP + swz(wr * 64 + mi * 16 + lo, kk * 64 + hi * 16));
#pragma unroll
      for (int ni = 0; ni < 4; ++ni) {
        bf16x8 vf = *(const bf16x8*)(sV + swz(wc * 64 + ni * 16 + lo, kk * 64 + hi * 16));
#pragma unroll
        for (int mi = 0; mi < 4; ++mi)
          acc[mi][ni] = __builtin_amdgcn_mfma_f32_16x16x32_bf16(pa[mi], vf, acc[mi][ni], 0, 0, 0);
      }
    }
    __builtin_amdgcn_s_setprio(0);
    __syncthreads();  // all sV/sP reads done; drains K(t+1) (vmcnt 0) + lgkm
    if (t < 63) {     // V(t+1) gloads into the (fully-read) single buffer
#pragma unroll
      for (int j = 0; j < 4; ++j)
        gload16(vSrcJ[j] + (size_t)(t + 1) * 128, sV + ((tid + j * 512) << 4));
    }
    cur ^= 1;
  }

  // ---- denominator: 4 per-quarter partials; reduce over hi via shfl; merge via LDS
#pragma unroll
  for (int j = 0; j < 4; ++j) {
    lsum[j] += __shfl_xor(lsum[j], 16, 64);
    lsum[j] += __shfl_xor(lsum[j], 32, 64);
  }
  float* lLds = (float*)smem;  // 512 floats in the (dead) sK region
  if (hi == 0) {
#pragma unroll
    for (int j = 0; j < 4; ++j)
      lLds[sh * 128 + qg * 64 + j * 16 + lo] = lsum[j];
  }
  __syncthreads();

#pragma unroll
  for (int mi = 0; mi < 4; ++mi)
#pragma unroll
    for (int r = 0; r < 4; ++r) {
      const int rloc = wr * 64 + mi * 16 + hi * 4 + r;
      const int grow = (int)qrow0 + rloc;
      const float linv = 1.0f / ((lLds[rloc] + lLds[128 + rloc]) +
                                 (lLds[256 + rloc] + lLds[384 + rloc]));
#pragma unroll
      for (int ni = 0; ni < 4; ++ni) {
        const int col = ck * 256 + wc * 64 + ni * 16 + lo;
        out[(size_t)grow * 1024 + col] = acc[mi][ni][r] * linv;
      }
    }
}

// ---------------------------------------------------------------- launch
extern "C" void kernel_launch(void* const* d_in, const int* in_sizes, int n_in,
                              void* d_out, int out_size, void* d_ws, size_t ws_size,
                              hipStream_t stream) {
  const float* x  = (const float*)d_in[0];
  const float* Wq = (const float*)d_in[1];
  const float* Wk = (const float*)d_in[2];
  const float* Wv = (const float*)d_in[3];

  char* ws = (char*)d_ws;
  unsigned short* xb    = (unsigned short*)(ws);               // 33,554,432 B
  unsigned short* wcat  = (unsigned short*)(ws + 33554432);    //  2,359,296 B
  unsigned short* qk    = (unsigned short*)(ws + 35913728);    //  4,194,304 B
  unsigned short* vT    = (unsigned short*)(ws + 40108032);    // 33,554,432 B

  const float SCALE_Q = 0.125f * 1.4426950408889634f;  // fold softmax scale+log2e into Wq

  cast_all_k<<<2048, 256, 0, stream>>>(x, Wq, Wk, Wv, xb, wcat, SCALE_Q);
  gemm_qkv_k<<<dim3(9, 128), 256, 0, stream>>>(xb, wcat, qk, vT);
  pv_k<<<dim3(4, 32, 4), 512, 0, stream>>>(qk, vT, (float*)d_out);
}

// Round 16
// 235.300 us; speedup vs baseline: 1.5764x; 1.5764x over previous
//
#include <hip/hip_runtime.h>

// TransformerHead: B=4, S=4096, D_MODEL=1024, D_K=64.  All-bf16 MFMA pipeline.
//   ws layout: xb(32MB) | Wcat(2.25MB) | qk(4MB) | vT(32MB)  ~= 70.4MB
// R1: T2 XOR-swizzle (conflicts 1.09e8 -> 0).  R3: swapped QK.  R4/R6: cvt_pk asm
// BANNED.  R9: per-lane strided global V gathers BANNED (FETCH 26x).
// R5/R7/R8/R10: conflict-free writes; stats_k dropped; VALU diet; fused cast: 249us.
// R11: s-tile 64, V gload16 single-buf, counted vmcnt: 240.2us (pv 178.5).
// R12: QK-one-tile-ahead FAILED (same-wave MFMA pipe -> no overlap). Reverted.
// R13: QK retile 2s x 4q (kf reads 8->4): 235.4us (pv 170.5, MfmaUtil 45.3).
// R14: QK retile 4s x 2q FAILED: qf[2][4] (+16 VGPR) broke the 128-VGPR cap of
//      __launch_bounds__(512,4) -> scratch spills (FETCH 48.5->290MB, pv 325us).
//      RULE: R13's register budget is at the wall; no more per-wave state.
// R15: exact R13 revert (recover 235.4us baseline).

#define DEV static __device__ __forceinline__

typedef __attribute__((ext_vector_type(8))) short bf16x8;
typedef __attribute__((ext_vector_type(4))) float f32x4;
typedef __attribute__((ext_vector_type(4))) unsigned short u16x4;
typedef __attribute__((ext_vector_type(8))) unsigned short u16x8;
typedef __attribute__((address_space(1))) void as1_void;
typedef __attribute__((address_space(3))) void as3_void;

DEV unsigned short f2bf(float f) {
  union { float f; unsigned u; } v; v.f = f;
  return (unsigned short)((v.u + 0x7FFFu + ((v.u >> 16) & 1u)) >> 16);
}

// pack bf16(a) (low16) | bf16(b) (high16), round-half-up, via v_perm_b32
DEV unsigned pk_bf16(float a, float b) {
  union { float f; unsigned u; } va, vb;
  va.f = a; vb.f = b;
  return __builtin_amdgcn_perm(vb.u + 0x8000u, va.u + 0x8000u, 0x07060302u);
}

DEV void gload16(const void* g, void* l) {
  __builtin_amdgcn_global_load_lds((as1_void*)g, (as3_void*)l, 16, 0, 0);
}

// 128B-row swizzle (rows of 64 bf16)
DEV int swz(int row, int cb) { return (row << 7) + (cb ^ ((row & 7) << 4)); }

// ---------------------------------------------------------------- fused cast f32->bf16
__global__ __launch_bounds__(256) void cast_all_k(
    const float* __restrict__ x, const float* __restrict__ wq,
    const float* __restrict__ wk, const float* __restrict__ wv,
    unsigned short* __restrict__ xb, unsigned short* __restrict__ wcat, float sq) {
  const int stride = gridDim.x * blockDim.x;
  for (int i = blockIdx.x * blockDim.x + threadIdx.x; i < 2244608; i += stride) {
    const float* src; unsigned short* dst; float scale; int j;
    if (i < 2097152)      { src = x;  dst = xb;            scale = 1.f; j = i; }
    else if (i < 2105344) { src = wq; dst = wcat;          scale = sq;  j = i - 2097152; }
    else if (i < 2113536) { src = wk; dst = wcat + 65536;  scale = 1.f; j = i - 2105344; }
    else                  { src = wv; dst = wcat + 131072; scale = 1.f; j = i - 2113536; }
    const float4* p = (const float4*)src + (size_t)j * 2;
    float4 a = p[0], b = p[1];
    u16x8 r;
    r[0] = f2bf(a.x * scale); r[1] = f2bf(a.y * scale);
    r[2] = f2bf(a.z * scale); r[3] = f2bf(a.w * scale);
    r[4] = f2bf(b.x * scale); r[5] = f2bf(b.y * scale);
    r[6] = f2bf(b.z * scale); r[7] = f2bf(b.w * scale);
    *(u16x8*)(dst + (size_t)j * 8) = r;
  }
}

// ---------------------------------------------------------------- QKV projection GEMM (unchanged)
__global__ __launch_bounds__(256, 2) void gemm_qkv_k(
    const unsigned short* __restrict__ xb, const unsigned short* __restrict__ wcat,
    unsigned short* __restrict__ qk, unsigned short* __restrict__ vT) {
  __shared__ __align__(16) unsigned char smem[65536];
  unsigned char* sA = smem;          // 2 x [128][64] bf16, swizzled
  unsigned char* sB = smem + 32768;  // 2 x [128][64] bf16, swizzled
  const int tid = threadIdx.x;
  const int w = tid >> 6, lane = tid & 63, lo = lane & 15, hi = lane >> 4;
  const int wr = w >> 1, wc = w & 1;
  const int bn = blockIdx.x, m0 = blockIdx.y * 128, n0 = bn * 128;
  const char* aBase = (const char*)xb + (size_t)m0 * 2048;
  const char* bBase = (const char*)wcat + (size_t)n0 * 2048;

  const int soff = ((w * 4) << 10) + (lane << 4);
  f32x4 acc[4][4];
  const f32x4 z = {0.f, 0.f, 0.f, 0.f};
#pragma unroll
  for (int mi = 0; mi < 4; ++mi)
#pragma unroll
    for (int ni = 0; ni < 4; ++ni) acc[mi][ni] = z;

#pragma unroll
  for (int r2 = 0; r2 < 4; ++r2) {
    const int off = soff + (r2 << 10);
    const int row = off >> 7;
    const int cbs = (off & 127) ^ ((row & 7) << 4);
    gload16(aBase + (size_t)row * 2048 + cbs, sA + ((w * 4 + r2) << 10));
    gload16(bBase + (size_t)row * 2048 + cbs, sB + ((w * 4 + r2) << 10));
  }
  __syncthreads();

  int cur = 0;
  for (int k0 = 0; k0 < 1024; k0 += 64) {
    if (k0 + 64 < 1024) {
      const int nb = (cur ^ 1) * 16384;
#pragma unroll
      for (int r2 = 0; r2 < 4; ++r2) {
        const int off = soff + (r2 << 10);
        const int row = off >> 7;
        const int cbs = (off & 127) ^ ((row & 7) << 4);
        gload16(aBase + (size_t)row * 2048 + (k0 + 64) * 2 + cbs, sA + nb + ((w * 4 + r2) << 10));
        gload16(bBase + (size_t)row * 2048 + (k0 + 64) * 2 + cbs, sB + nb + ((w * 4 + r2) << 10));
      }
    }
    const int cb0 = cur * 16384;
#pragma unroll
    for (int kk = 0; kk < 2; ++kk) {
      const int cb = kk * 64 + hi * 16;
      bf16x8 af[4], bfv[4];
#pragma unroll
      for (int mi = 0; mi < 4; ++mi)
        af[mi] = *(const bf16x8*)(sA + cb0 + swz(wr * 64 + mi * 16 + lo, cb));
#pragma unroll
      for (int ni = 0; ni < 4; ++ni)
        bfv[ni] = *(const bf16x8*)(sB + cb0 + swz(wc * 64 + ni * 16 + lo, cb));
#pragma unroll
      for (int mi = 0; mi < 4; ++mi)
#pragma unroll
        for (int ni = 0; ni < 4; ++ni)
          acc[mi][ni] = __builtin_amdgcn_mfma_f32_16x16x32_bf16(af[mi], bfv[ni], acc[mi][ni], 0, 0, 0);
    }
    __syncthreads();
    cur ^= 1;
  }

  if (bn == 0) {
#pragma unroll
    for (int mi = 0; mi < 4; ++mi) {
      const int row = m0 + wr * 64 + mi * 16 + hi * 4;
#pragma unroll
      for (int ni = 0; ni < 4; ++ni) {
        const int col = wc * 64 + ni * 16 + lo;
#pragma unroll
        for (int r = 0; r < 4; ++r)
          qk[(size_t)(row + r) * 128 + col] = f2bf(acc[mi][ni][r]);
      }
    }
  } else {
#pragma unroll
    for (int mi = 0; mi < 4; ++mi) {
      const int grow = m0 + wr * 64 + mi * 16 + hi * 4;
      const int b = grow >> 12, s = grow & 4095;
#pragma unroll
      for (int ni = 0; ni < 4; ++ni) {
        const int vcol = (n0 - 128) + wc * 64 + ni * 16 + lo;
        u16x4 pk;
#pragma unroll
        for (int r = 0; r < 4; ++r) pk[r] = f2bf(acc[mi][ni][r]);
        *(u16x4*)(vT + (size_t)(b * 1024 + vcol) * 4096 + s) = pk;
      }
    }
  }
}

// ---------------------------------------------------------------- PV pass (R13 exact)
// Block: 128 q x 256 v, 8 waves, s-tile 64.  QK wave grid: 2(s-half) x 4(q-group),
// wave = 32s x 32q -> 4 kf reads.  PV wave grid: 2x4 (64q x 64v).
// LDS: sK 2x[64][128B] 16KB | sV [256][128B] 32KB single | sP [128][128B] 16KB = 64KB.
__global__ __launch_bounds__(512, 4) void pv_k(
    const unsigned short* __restrict__ qk, const unsigned short* __restrict__ vT,
    float* __restrict__ out) {
  __shared__ __align__(16) unsigned char smem[65536];
  unsigned char* sK = smem;          // 2 x [64][128B], swz128
  unsigned char* sV = smem + 16384;  // [256][128B] single buf, swz128
  unsigned char* sP = smem + 49152;  // [128][128B], swz128
  const int tid = threadIdx.x;
  const int w = tid >> 6, lane = tid & 63, lo = lane & 15, hi = lane >> 4;
  const int wr = w >> 2, wc = w & 3;   // PV role: 2x4 wave grid over 128x256
  const int sh = w & 1, qg = w >> 1;   // QK role: s-half x q-group (32s x 32q)
  const int ck = blockIdx.x, qt = blockIdx.y, b = blockIdx.z;
  const char* qkB = (const char*)qk;
  const char* vTB = (const char*)vT;
  const size_t qrow0 = (size_t)(b * 4096 + qt * 128);
  const f32x4 z = {0.f, 0.f, 0.f, 0.f};

  // Q frags (pre-scaled by 0.125*log2e at cast): 2 q-subgroups x 2 kk, global -> regs once.
  bf16x8 qf[2][2];
#pragma unroll
  for (int kk = 0; kk < 2; ++kk)
#pragma unroll
    for (int j = 0; j < 2; ++j)
      qf[kk][j] = *(const bf16x8*)(qkB + (qrow0 + qg * 32 + j * 16 + lo) * 256 + kk * 64 + hi * 16);
  float lsum0 = 0.f, lsum1 = 0.f;  // partials for q = qg*32 + {0,16} + lo over this wave's 32 s

  // K staging: tile [64s][64d]=8KB, 1 issue/wave; chunk kc: row=kc>>3, g=kc&7
  const int kc = w * 64 + lane;
  const int kRow = kc >> 3, kG = kc & 7;
  const char* kSrc = qkB + (size_t)(b * 4096 + kRow) * 256 + 128 + ((kG ^ (kRow & 7)) << 4);
  unsigned char* kDst = sK + (kc << 4);  // + buf*8192

  // V staging: tile [256v][64s]=32KB, 4 issues/lane; pre-swizzled source (rule #21)
  const char* vSrcJ[4];
#pragma unroll
  for (int j = 0; j < 4; ++j) {
    const int c = tid + j * 512;
    const int row = c >> 3, g = c & 7;
    vSrcJ[j] = vTB + (size_t)(b * 1024 + ck * 256 + row) * 8192 + ((g ^ (row & 7)) << 4);
  }

  // sP b64 write addrs: row q = qg*32 + j*16 + lo (q&7 == lo&7); s0 = sh*32 + n*16 + 4*hi
  // granule = sh*4 + n*2 + (hi>>1), slot XOR (lo&7); +8B for hi&1.
  const int lx7 = (lo & 7) << 4;
  int aP[2][2];
#pragma unroll
  for (int n = 0; n < 2; ++n)
#pragma unroll
    for (int j = 0; j < 2; ++j)
      aP[n][j] = ((qg * 32 + j * 16 + lo) << 7) +
                 (((sh * 4 + n * 2 + (hi >> 1)) << 4) ^ lx7) + ((hi & 1) << 3);

  f32x4 acc[4][4];
#pragma unroll
  for (int mi = 0; mi < 4; ++mi)
#pragma unroll
    for (int ni = 0; ni < 4; ++ni) acc[mi][ni] = z;

  // prologue: V(0) + K(0) -> full drain
#pragma unroll
  for (int j = 0; j < 4; ++j) gload16(vSrcJ[j], sV + ((tid + j * 512) << 4));
  gload16(kSrc, kDst);
  __syncthreads();  // drains vmcnt(0) lgkmcnt(0)

  int cur = 0;
  for (int t = 0; t < 64; ++t) {
    // K(t+1) -> buf^1 (wraps harmlessly at t=63 to keep vmcnt counts uniform)
    gload16(kSrc + (size_t)((t + 1) & 63) * 16384, kDst + (cur ^ 1) * 8192);
    // ---- QK(t): wave computes S[sh*32 .. +32][qg*32 .. +32]; lane owns q cols
    f32x4 sv00 = z, sv01 = z, sv10 = z, sv11 = z;
#pragma unroll
    for (int kk = 0; kk < 2; ++kk) {
      bf16x8 kf0 = *(const bf16x8*)(sK + cur * 8192 + swz(sh * 32 + lo, kk * 64 + hi * 16));
      bf16x8 kf1 = *(const bf16x8*)(sK + cur * 8192 + swz(sh * 32 + 16 + lo, kk * 64 + hi * 16));
      sv00 = __builtin_amdgcn_mfma_f32_16x16x32_bf16(kf0, qf[kk][0], sv00, 0, 0, 0);
      sv01 = __builtin_amdgcn_mfma_f32_16x16x32_bf16(kf0, qf[kk][1], sv01, 0, 0, 0);
      sv10 = __builtin_amdgcn_mfma_f32_16x16x32_bf16(kf1, qf[kk][0], sv10, 0, 0, 0);
      sv11 = __builtin_amdgcn_mfma_f32_16x16x32_bf16(kf1, qf[kk][1], sv11, 0, 0, 0);
    }
    // ---- exp2 (unnormalized) + l partials + 4x b64 P writes
    {
      const float a0 = __builtin_amdgcn_exp2f(sv00[0]);
      const float a1 = __builtin_amdgcn_exp2f(sv00[1]);
      const float a2 = __builtin_amdgcn_exp2f(sv00[2]);
      const float a3 = __builtin_amdgcn_exp2f(sv00[3]);
      const float b0 = __builtin_amdgcn_exp2f(sv01[0]);
      const float b1 = __builtin_amdgcn_exp2f(sv01[1]);
      const float b2 = __builtin_amdgcn_exp2f(sv01[2]);
      const float b3 = __builtin_amdgcn_exp2f(sv01[3]);
      const float c0 = __builtin_amdgcn_exp2f(sv10[0]);
      const float c1 = __builtin_amdgcn_exp2f(sv10[1]);
      const float c2 = __builtin_amdgcn_exp2f(sv10[2]);
      const float c3 = __builtin_amdgcn_exp2f(sv10[3]);
      const float d0 = __builtin_amdgcn_exp2f(sv11[0]);
      const float d1 = __builtin_amdgcn_exp2f(sv11[1]);
      const float d2 = __builtin_amdgcn_exp2f(sv11[2]);
      const float d3 = __builtin_amdgcn_exp2f(sv11[3]);
      lsum0 += ((a0 + a1) + (a2 + a3)) + ((c0 + c1) + (c2 + c3));
      lsum1 += ((b0 + b1) + (b2 + b3)) + ((d0 + d1) + (d2 + d3));
      uint2 wA, wB, wC, wD;
      wA.x = pk_bf16(a0, a1); wA.y = pk_bf16(a2, a3);
      wB.x = pk_bf16(b0, b1); wB.y = pk_bf16(b2, b3);
      wC.x = pk_bf16(c0, c1); wC.y = pk_bf16(c2, c3);
      wD.x = pk_bf16(d0, d1); wD.y = pk_bf16(d2, d3);
      *(uint2*)(sP + aP[0][0]) = wA;
      *(uint2*)(sP + aP[0][1]) = wB;
      *(uint2*)(sP + aP[1][0]) = wC;
      *(uint2*)(sP + aP[1][1]) = wD;
    }
    // ---- mid barrier: V(t) landed (vmcnt(1) leaves K(t+1) in flight), P visible
    asm volatile("s_waitcnt vmcnt(1) lgkmcnt(0)" ::: "memory");
    __builtin_amdgcn_sched_barrier(0);
    __builtin_amdgcn_s_barrier();
    __builtin_amdgcn_sched_barrier(0);
    // ---- PV(t): wave (wr,wc), rows wr*64..+64, cols wc*64..+64, k=64 (2 kk halves)
    __builtin_amdgcn_s_setprio(1);
#pragma unroll
    for (int kk = 0; kk < 2; ++kk) {
      bf16x8 pa[4];
#pragma unroll
      for (int mi = 0; mi < 4; ++mi)
        pa[mi] = *(const bf16x8*)(sP + swz(wr * 64 + mi * 16 + lo, kk * 64 + hi * 16));
#pragma unroll
      for (int ni = 0; ni < 4; ++ni) {
        bf16x8 vf = *(const bf16x8*)(sV + swz(wc * 64 + ni * 16 + lo, kk * 64 + hi * 16));
#pragma unroll
        for (int mi = 0; mi < 4; ++mi)
          acc[mi][ni] = __builtin_amdgcn_mfma_f32_16x16x32_bf16(pa[mi], vf, acc[mi][ni], 0, 0, 0);
      }
    }
    __builtin_amdgcn_s_setprio(0);
    __syncthreads();  // all sV/sP reads done; drains K(t+1) (vmcnt 0) + lgkm
    if (t < 63) {     // V(t+1) gloads into the (fully-read) single buffer
#pragma unroll
      for (int j = 0; j < 4; ++j)
        gload16(vSrcJ[j] + (size_t)(t + 1) * 128, sV + ((tid + j * 512) << 4));
    }
    cur ^= 1;
  }

  // ---- denominator: per-half partials; reduce over hi via shfl; merge halves via LDS
  lsum0 += __shfl_xor(lsum0, 16, 64);
  lsum0 += __shfl_xor(lsum0, 32, 64);
  lsum1 += __shfl_xor(lsum1, 16, 64);
  lsum1 += __shfl_xor(lsum1, 32, 64);
  float* lLds = (float*)smem;  // 256 floats in the (dead) sK region
  if (hi == 0) {
    lLds[sh * 128 + qg * 32 + lo] = lsum0;
    lLds[sh * 128 + qg * 32 + 16 + lo] = lsum1;
  }
  __syncthreads();

#pragma unroll
  for (int mi = 0; mi < 4; ++mi)
#pragma unroll
    for (int r = 0; r < 4; ++r) {
      const int rloc = wr * 64 + mi * 16 + hi * 4 + r;
      const int grow = (int)qrow0 + rloc;
      const float linv = 1.0f / (lLds[rloc] + lLds[128 + rloc]);
#pragma unroll
      for (int ni = 0; ni < 4; ++ni) {
        const int col = ck * 256 + wc * 64 + ni * 16 + lo;
        out[(size_t)grow * 1024 + col] = acc[mi][ni][r] * linv;
      }
    }
}

// ---------------------------------------------------------------- launch
extern "C" void kernel_launch(void* const* d_in, const int* in_sizes, int n_in,
                              void* d_out, int out_size, void* d_ws, size_t ws_size,
                              hipStream_t stream) {
  const float* x  = (const float*)d_in[0];
  const float* Wq = (const float*)d_in[1];
  const float* Wk = (const float*)d_in[2];
  const float* Wv = (const float*)d_in[3];

  char* ws = (char*)d_ws;
  unsigned short* xb    = (unsigned short*)(ws);               // 33,554,432 B
  unsigned short* wcat  = (unsigned short*)(ws + 33554432);    //  2,359,296 B
  unsigned short* qk    = (unsigned short*)(ws + 35913728);    //  4,194,304 B
  unsigned short* vT    = (unsigned short*)(ws + 40108032);    // 33,554,432 B

  const float SCALE_Q = 0.125f * 1.4426950408889634f;  // fold softmax scale+log2e into Wq

  cast_all_k<<<2048, 256, 0, stream>>>(x, Wq, Wk, Wv, xb, wcat, SCALE_Q);
  gemm_qkv_k<<<dim3(9, 128), 256, 0, stream>>>(xb, wcat, qk, vT);
  pv_k<<<dim3(4, 32, 4), 512, 0, stream>>>(qk, vT, (float*)d_out);
}